// Round 1
// baseline (394.308 us; speedup 1.0000x reference)
//
#include <hip/hip_runtime.h>

// Problem: Reinsertion_7739531067800
// B=32, G=512, D=128, H=4, KD=32. Output (B,G,G) fp32.
//
// Math restructure:
//   c_pp[b,g,h] = dot_d(h[b,g,:],  Apq[b,h,:]),  Apq[b,h,d] = NORM*sum_k Q1p[b,h,k]*Wk1[h,d,k]
//   c_po[b,g,h] = dot_d(h[b,rec,:],Apo[b,h,:]),  Apo from Q2p (pickup@Wq2) and Wk2
//   c_dp[b,g,h] = dot_d(h[b,g,:],  Adp[b,h,:]),  Adp from Q1d (delivery@Wq1) and Wk1
//   c_do[b,g,h] = dot_d(h[b,rec,:],Ado[b,h,:]),  Ado from Q2d (delivery@Wq2) and Wk2
//   Layer1 decomposes: relu(x@W1+b1) = relu(P[b,g1] + Q[b,g2])
//     P[b,g1,:] = [c_pp,c_po]@W1[0:8,:]          (varies with g1 only)
//     Q[b,g2,:] = [c_dp,c_do]@W1[8:16,:] + b1    (varies with g2 only)
//   Per-pair work: a=relu(P+Q); z=relu(a@W2+b2); out = z@w3 + b3.

#define B 32
#define G 512
#define D 128
#define NH 4
#define KD 32
#define NORMF 0.17677669529663687f  // 1/sqrt(32)

// ws layout (floats):
//  [0      .. 16384): Apq  [b*512 + h*128 + d]
//  [16384  .. 32768): Apo
//  [32768  .. 49152): Adp
//  [49152  .. 65536): Ado
//  [65536  .. 65536+524288): P  [(b*G+g)*32 + j]
//  [589824 .. 589824+524288): Q
#define WS_APQ 0
#define WS_APO 16384
#define WS_ADP 32768
#define WS_ADO 49152
#define WS_P   65536
#define WS_Q   589824

// ---------------- Stage 0: per-batch A matrices (tiny) ----------------
__global__ __launch_bounds__(128) void precompute_A(
    const float* __restrict__ h, const int* __restrict__ pp, const int* __restrict__ pd,
    const float* __restrict__ Wq1, const float* __restrict__ Wk1,
    const float* __restrict__ Wq2, const float* __restrict__ Wk2,
    float* __restrict__ ws) {
  const int b = blockIdx.x;
  const int t = threadIdx.x;  // 0..127
  __shared__ float hp[D], hd[D];
  __shared__ float q1p[NH * KD], q2p[NH * KD], q1d[NH * KD], q2d[NH * KD];

  hp[t] = h[(b * G + pp[b]) * D + t];
  hd[t] = h[(b * G + pd[b]) * D + t];
  __syncthreads();

  {  // t -> (head hh, key k); dot over d
    const int hh = t >> 5, k = t & 31;
    const float* wq1 = Wq1 + hh * D * KD + k;
    const float* wq2 = Wq2 + hh * D * KD + k;
    float s1p = 0.f, s2p = 0.f, s1d = 0.f, s2d = 0.f;
    for (int d = 0; d < D; ++d) {
      const float w1 = wq1[d * KD], w2 = wq2[d * KD];
      const float xp = hp[d], xd = hd[d];
      s1p = fmaf(xp, w1, s1p);
      s2p = fmaf(xp, w2, s2p);
      s1d = fmaf(xd, w1, s1d);
      s2d = fmaf(xd, w2, s2d);
    }
    q1p[t] = s1p; q2p[t] = s2p; q1d[t] = s1d; q2d[t] = s2d;
  }
  __syncthreads();

  // A[b,h,d] = NORM * sum_k q[h,k] * Wk[h,d,k];  thread t handles d=t, all 4 heads
  const int d = t;
  for (int hh = 0; hh < NH; ++hh) {
    const float* wk1 = Wk1 + hh * D * KD + d * KD;
    const float* wk2 = Wk2 + hh * D * KD + d * KD;
    float apq = 0.f, apo = 0.f, adp = 0.f, ado = 0.f;
#pragma unroll
    for (int k = 0; k < KD; ++k) {
      const float w1 = wk1[k], w2 = wk2[k];
      apq = fmaf(q1p[hh * 32 + k], w1, apq);
      adp = fmaf(q1d[hh * 32 + k], w1, adp);
      apo = fmaf(q2p[hh * 32 + k], w2, apo);
      ado = fmaf(q2d[hh * 32 + k], w2, ado);
    }
    const int o = b * (NH * D) + hh * D + d;
    ws[WS_APQ + o] = NORMF * apq;
    ws[WS_APO + o] = NORMF * apo;
    ws[WS_ADP + o] = NORMF * adp;
    ws[WS_ADO + o] = NORMF * ado;
  }
}

// ---------------- Stage 1: P and Q vectors (small) ----------------
__global__ __launch_bounds__(256) void compute_PQ(
    const float* __restrict__ h, const int* __restrict__ rec,
    const float* __restrict__ fc1_w, const float* __restrict__ fc1_b,
    float* __restrict__ ws) {
  const int idx = blockIdx.x * 256 + threadIdx.x;  // 0..16383
  const int b = idx >> 9, g = idx & 511;           // b uniform per block (512 g per b)
  const float* hg = h + (b * G + g) * D;
  const float* hn = h + (b * G + rec[b * G + g]) * D;
  const float* Apq = ws + WS_APQ + b * (NH * D);
  const float* Apo = ws + WS_APO + b * (NH * D);
  const float* Adp = ws + WS_ADP + b * (NH * D);
  const float* Ado = ws + WS_ADO + b * (NH * D);

  float cpp[NH] = {0.f, 0.f, 0.f, 0.f};
  float cpo[NH] = {0.f, 0.f, 0.f, 0.f};
  float cdp[NH] = {0.f, 0.f, 0.f, 0.f};
  float cdo[NH] = {0.f, 0.f, 0.f, 0.f};
  for (int d = 0; d < D; ++d) {
    const float x = hg[d], y = hn[d];
#pragma unroll
    for (int hh = 0; hh < NH; ++hh) {
      cpp[hh] = fmaf(x, Apq[hh * D + d], cpp[hh]);
      cdp[hh] = fmaf(x, Adp[hh * D + d], cdp[hh]);
      cpo[hh] = fmaf(y, Apo[hh * D + d], cpo[hh]);
      cdo[hh] = fmaf(y, Ado[hh * D + d], cdo[hh]);
    }
  }
  float u[8], v[8];
#pragma unroll
  for (int i = 0; i < 4; ++i) {
    u[i] = cpp[i]; u[4 + i] = cpo[i];
    v[i] = cdp[i]; v[4 + i] = cdo[i];
  }
  float* P = ws + WS_P + (b * G + g) * 32;
  float* Q = ws + WS_Q + (b * G + g) * 32;
#pragma unroll 8
  for (int j = 0; j < 32; ++j) {
    float p = 0.f, q = fc1_b[j];
#pragma unroll
    for (int i = 0; i < 8; ++i) {
      p = fmaf(u[i], fc1_w[i * 32 + j], p);
      q = fmaf(v[i], fc1_w[(8 + i) * 32 + j], q);
    }
    P[j] = p; Q[j] = q;
  }
}

// ---------------- Stage 2: per-pair MLP (dominant) ----------------
// Block: 256 threads = 4 g1 x 64 g2 tile. Stores coalesced 256B/wave.
#define TM 4
#define TN 64
__global__ __launch_bounds__(256) void mlp_pairs(
    const float* __restrict__ ws,
    const float* __restrict__ fc2_w, const float* __restrict__ fc2_b,
    const float* __restrict__ fc3_w, const float* __restrict__ fc3_b,
    float* __restrict__ out) {
  const int b = blockIdx.z;
  const int g1_0 = blockIdx.y * TM;
  const int g2_0 = blockIdx.x * TN;
  const float* Pg = ws + WS_P + (b * G + g1_0) * 32;
  const float* Qg = ws + WS_Q + (b * G + g2_0) * 32;

  __shared__ float sP[TM][32];
  __shared__ float sQ[TN][33];  // pad -> 2-way bank aliasing only (free)

  const int t = threadIdx.x;
  if (t < TM * 32) sP[t >> 5][t & 31] = Pg[t];
#pragma unroll
  for (int m = t; m < TN * 32; m += 256) sQ[m >> 5][m & 31] = Qg[m];
  __syncthreads();

  const int tx = t & 63;  // g2 offset; consecutive lanes -> consecutive g2
  const int ty = t >> 6;  // g1 offset; uniform per wave

  float a[32];
#pragma unroll
  for (int i = 0; i < 32; ++i) a[i] = fmaxf(sP[ty][i] + sQ[tx][i], 0.f);

  // fc2 + relu + fc3. Weight indices are wave-uniform -> s_load path.
  float acc = fc3_b[0];
#pragma unroll
  for (int j = 0; j < 32; ++j) {
    float s = fc2_b[j];
#pragma unroll
    for (int i = 0; i < 32; ++i) s = fmaf(a[i], fc2_w[i * 32 + j], s);
    acc = fmaf(fmaxf(s, 0.f), fc3_w[j], acc);
  }
  out[(b * G + g1_0 + ty) * G + g2_0 + tx] = acc;
}

extern "C" void kernel_launch(void* const* d_in, const int* in_sizes, int n_in,
                              void* d_out, int out_size, void* d_ws, size_t ws_size,
                              hipStream_t stream) {
  const float* h     = (const float*)d_in[0];
  const int*   pp    = (const int*)d_in[1];
  const int*   pd    = (const int*)d_in[2];
  const int*   rec   = (const int*)d_in[3];
  const float* Wq1   = (const float*)d_in[4];
  const float* Wk1   = (const float*)d_in[5];
  const float* Wq2   = (const float*)d_in[6];
  const float* Wk2   = (const float*)d_in[7];
  const float* fc1_w = (const float*)d_in[8];
  const float* fc1_b = (const float*)d_in[9];
  const float* fc2_w = (const float*)d_in[10];
  const float* fc2_b = (const float*)d_in[11];
  const float* fc3_w = (const float*)d_in[12];
  const float* fc3_b = (const float*)d_in[13];
  float* out = (float*)d_out;
  float* ws  = (float*)d_ws;

  precompute_A<<<dim3(B), dim3(128), 0, stream>>>(h, pp, pd, Wq1, Wk1, Wq2, Wk2, ws);
  compute_PQ<<<dim3((B * G) / 256), dim3(256), 0, stream>>>(h, rec, fc1_w, fc1_b, ws);
  mlp_pairs<<<dim3(G / TN, G / TM, B), dim3(256), 0, stream>>>(
      ws, fc2_w, fc2_b, fc3_w, fc3_b, out);
}

// Round 2
// 180.019 us; speedup vs baseline: 2.1904x; 2.1904x over previous
//
#include <hip/hip_runtime.h>

// Reinsertion: B=32, G=512, D=128, H=4, KD=32. Output (B,G,G) fp32.
//
// R2: stage-2 pair-MLP moved to MFMA (16x16x32 bf16, hi/lo split for ~fp32
// precision). fc2 computed transposed: D[n][pair] = W2t[n][k] * aT[k][pair]
// so C-layout col(lane&15) = pair -> fc3 reduce = 2 shfl_xor per 16 pairs.

#define B 32
#define G 512
#define D 128
#define NH 4
#define KD 32
#define NORMF 0.17677669529663687f  // 1/sqrt(32)

#define WS_APQ 0
#define WS_APO 16384
#define WS_ADP 32768
#define WS_ADO 49152
#define WS_P   65536
#define WS_Q   589824

typedef float v4f __attribute__((ext_vector_type(4)));
typedef short v8s __attribute__((ext_vector_type(8)));  // 8 bf16 (4 VGPRs)

// Truncating bf16 hi/lo split of two fp32 (inputs >= 0 post-relu).
// hi = {bf16_trunc(f1), bf16_trunc(f0)} packed; lo captures next 8+ bits.
__device__ __forceinline__ void split2(float f0, float f1,
                                       unsigned& hi, unsigned& lo) {
  unsigned b0 = __float_as_uint(f0), b1 = __float_as_uint(f1);
  float r0 = f0 - __uint_as_float(b0 & 0xffff0000u);
  float r1 = f1 - __uint_as_float(b1 & 0xffff0000u);
  hi = __builtin_amdgcn_perm(b1, b0, 0x07060302);  // {b1.hi16, b0.hi16}
  lo = __builtin_amdgcn_perm(__float_as_uint(r1), __float_as_uint(r0),
                             0x07060302);
}

// ---------------- Stage 0: per-batch A matrices (tiny) ----------------
__global__ __launch_bounds__(128) void precompute_A(
    const float* __restrict__ h, const int* __restrict__ pp, const int* __restrict__ pd,
    const float* __restrict__ Wq1, const float* __restrict__ Wk1,
    const float* __restrict__ Wq2, const float* __restrict__ Wk2,
    float* __restrict__ ws) {
  const int b = blockIdx.x;
  const int t = threadIdx.x;  // 0..127
  __shared__ float hp[D], hd[D];
  __shared__ float q1p[NH * KD], q2p[NH * KD], q1d[NH * KD], q2d[NH * KD];

  hp[t] = h[(b * G + pp[b]) * D + t];
  hd[t] = h[(b * G + pd[b]) * D + t];
  __syncthreads();

  {  // t -> (head hh, key k); dot over d
    const int hh = t >> 5, k = t & 31;
    const float* wq1 = Wq1 + hh * D * KD + k;
    const float* wq2 = Wq2 + hh * D * KD + k;
    float s1p = 0.f, s2p = 0.f, s1d = 0.f, s2d = 0.f;
    for (int d = 0; d < D; ++d) {
      const float w1 = wq1[d * KD], w2 = wq2[d * KD];
      const float xp = hp[d], xd = hd[d];
      s1p = fmaf(xp, w1, s1p);
      s2p = fmaf(xp, w2, s2p);
      s1d = fmaf(xd, w1, s1d);
      s2d = fmaf(xd, w2, s2d);
    }
    q1p[t] = s1p; q2p[t] = s2p; q1d[t] = s1d; q2d[t] = s2d;
  }
  __syncthreads();

  const int d = t;
  for (int hh = 0; hh < NH; ++hh) {
    const float* wk1 = Wk1 + hh * D * KD + d * KD;
    const float* wk2 = Wk2 + hh * D * KD + d * KD;
    float apq = 0.f, apo = 0.f, adp = 0.f, ado = 0.f;
#pragma unroll
    for (int k = 0; k < KD; ++k) {
      const float w1 = wk1[k], w2 = wk2[k];
      apq = fmaf(q1p[hh * 32 + k], w1, apq);
      adp = fmaf(q1d[hh * 32 + k], w1, adp);
      apo = fmaf(q2p[hh * 32 + k], w2, apo);
      ado = fmaf(q2d[hh * 32 + k], w2, ado);
    }
    const int o = b * (NH * D) + hh * D + d;
    ws[WS_APQ + o] = NORMF * apq;
    ws[WS_APO + o] = NORMF * apo;
    ws[WS_ADP + o] = NORMF * adp;
    ws[WS_ADO + o] = NORMF * ado;
  }
}

// ---------------- Stage 1: P and Q vectors ----------------
// 256 blocks = (b, 64-g chunk). Thread: (gl = g-offset, hh = head/wave).
// A-tables read via wave-uniform pointers -> s_load_dwordx4.
__global__ __launch_bounds__(256) void compute_PQ(
    const float* __restrict__ h, const int* __restrict__ rec,
    const float* __restrict__ fc1_w, const float* __restrict__ fc1_b,
    float* __restrict__ ws) {
  const int bx = blockIdx.x;
  const int b = bx >> 3, g0 = (bx & 7) * 64;
  const int t = threadIdx.x;
  const int gl = t & 63;
  const int hh = __builtin_amdgcn_readfirstlane(t >> 6);  // wave id == head
  const int g = g0 + gl;

  __shared__ float sc[64][17];
  __shared__ float sout[64][33];

  const float* Apq = ws + WS_APQ + (b * NH + hh) * D;
  const float* Apo = ws + WS_APO + (b * NH + hh) * D;
  const float* Adp = ws + WS_ADP + (b * NH + hh) * D;
  const float* Ado = ws + WS_ADO + (b * NH + hh) * D;
  const float4* hg4 = (const float4*)(h + ((size_t)b * G + g) * D);
  const float4* hn4 = (const float4*)(h + ((size_t)b * G + rec[b * G + g]) * D);

  float cpp = 0.f, cpo = 0.f, cdp = 0.f, cdo = 0.f;
#pragma unroll 4
  for (int d4 = 0; d4 < 32; ++d4) {
    const float4 x = hg4[d4], y = hn4[d4];
    const float4 a1 = *(const float4*)(Apq + d4 * 4);
    const float4 a2 = *(const float4*)(Apo + d4 * 4);
    const float4 a3 = *(const float4*)(Adp + d4 * 4);
    const float4 a4 = *(const float4*)(Ado + d4 * 4);
    cpp = fmaf(x.x, a1.x, fmaf(x.y, a1.y, fmaf(x.z, a1.z, fmaf(x.w, a1.w, cpp))));
    cpo = fmaf(y.x, a2.x, fmaf(y.y, a2.y, fmaf(y.z, a2.z, fmaf(y.w, a2.w, cpo))));
    cdp = fmaf(x.x, a3.x, fmaf(x.y, a3.y, fmaf(x.z, a3.z, fmaf(x.w, a3.w, cdp))));
    cdo = fmaf(y.x, a4.x, fmaf(y.y, a4.y, fmaf(y.z, a4.z, fmaf(y.w, a4.w, cdo))));
  }
  sc[gl][hh] = cpp; sc[gl][4 + hh] = cpo; sc[gl][8 + hh] = cdp; sc[gl][12 + hh] = cdo;
  __syncthreads();

  float u[16];
#pragma unroll
  for (int i = 0; i < 16; ++i) u[i] = sc[gl][i];

  float pv[8], qv[8];
#pragma unroll
  for (int jj = 0; jj < 8; ++jj) {
    const int j = hh * 8 + jj;  // wave-uniform -> s_load weights
    float p = 0.f, q = fc1_b[j];
#pragma unroll
    for (int i = 0; i < 8; ++i) {
      p = fmaf(u[i], fc1_w[i * 32 + j], p);
      q = fmaf(u[8 + i], fc1_w[(8 + i) * 32 + j], q);
    }
    pv[jj] = p; qv[jj] = q;
  }

  // P: transpose through LDS for coalesced stores
#pragma unroll
  for (int jj = 0; jj < 8; ++jj) sout[gl][hh * 8 + jj] = pv[jj];
  __syncthreads();
  {
    float* dst = ws + WS_P + ((size_t)b * G + g0) * 32;
#pragma unroll
    for (int i = t; i < 2048; i += 256) dst[i] = sout[i >> 5][i & 31];
  }
  __syncthreads();
#pragma unroll
  for (int jj = 0; jj < 8; ++jj) sout[gl][hh * 8 + jj] = qv[jj];
  __syncthreads();
  {
    float* dst = ws + WS_Q + ((size_t)b * G + g0) * 32;
#pragma unroll
    for (int i = t; i < 2048; i += 256) dst[i] = sout[i >> 5][i & 31];
  }
}

// ---------------- Stage 2: per-pair MLP via MFMA ----------------
// Block: 256 thr = 4 waves. Tile: 16 g1 x 128 g2. Wave w owns g2-chunks
// {2w, 2w+1} (Q in VGPRs for whole block). Loop over 16 g1 (P from LDS).
// Group = (g1, chunk) = 16 pairs: B-frag[k][pair] = relu(P+Q) hi/lo,
// A-frag = W2t[n][k] hi/lo; 3 MFMAs per n-half; acc init = fc2 bias.
__global__ __launch_bounds__(256) void mlp_pairs(
    const float* __restrict__ ws,
    const float* __restrict__ fc2_w, const float* __restrict__ fc2_b,
    const float* __restrict__ fc3_w, const float* __restrict__ fc3_b,
    float* __restrict__ out) {
  const int b = blockIdx.z;
  const int g1_0 = blockIdx.y * 16;
  const int g2_0 = blockIdx.x * 128;
  const int t = threadIdx.x;
  const int w = t >> 6, l = t & 63;
  const int quad = l >> 4, lane15 = l & 15;
  const int k0 = quad * 8;

  __shared__ float sP[16 * 32];
  {
    const float* Pg = ws + WS_P + ((size_t)b * G + g1_0) * 32;
    sP[t] = Pg[t];
    sP[t + 256] = Pg[t + 256];
  }

  // Weight A-frags: W2t[n][k] = fc2_w[k*32+n]; halves n(+0), n(+16); hi/lo.
  v8s whi0, wlo0, whi1, wlo1;
  {
    unsigned* H0 = (unsigned*)&whi0; unsigned* L0 = (unsigned*)&wlo0;
    unsigned* H1 = (unsigned*)&whi1; unsigned* L1 = (unsigned*)&wlo1;
#pragma unroll
    for (int jp = 0; jp < 4; ++jp) {
      const int ka = k0 + 2 * jp, kb = ka + 1;
      split2(fc2_w[ka * 32 + lane15],      fc2_w[kb * 32 + lane15],      H0[jp], L0[jp]);
      split2(fc2_w[ka * 32 + 16 + lane15], fc2_w[kb * 32 + 16 + lane15], H1[jp], L1[jp]);
    }
  }
  v4f bias0, bias1;
  float w3a[4], w3b[4];
#pragma unroll
  for (int r = 0; r < 4; ++r) {
    const int n = quad * 4 + r;
    bias0[r] = fc2_b[n];      bias1[r] = fc2_b[n + 16];
    w3a[r]   = fc3_w[n];      w3b[r]   = fc3_w[n + 16];
  }
  const float b3 = fc3_b[0];

  // Q fragments: lane holds Q[g2][k0..k0+7] fp32 for its pair in each chunk.
  float4 q[2][2];
#pragma unroll
  for (int c = 0; c < 2; ++c) {
    const float* qp = ws + WS_Q +
        ((size_t)b * G + g2_0 + (2 * w + c) * 16 + lane15) * 32 + k0;
    q[c][0] = *(const float4*)qp;
    q[c][1] = *(const float4*)(qp + 4);
  }
  __syncthreads();

  const size_t outbase = ((size_t)b * G + g1_0) * G + g2_0;
  for (int g1 = 0; g1 < 16; ++g1) {
    const float4 p0 = *(const float4*)&sP[g1 * 32 + k0];
    const float4 p1 = *(const float4*)&sP[g1 * 32 + k0 + 4];
#pragma unroll
    for (int c = 0; c < 2; ++c) {
      float f[8];
      f[0] = fmaxf(p0.x + q[c][0].x, 0.f);
      f[1] = fmaxf(p0.y + q[c][0].y, 0.f);
      f[2] = fmaxf(p0.z + q[c][0].z, 0.f);
      f[3] = fmaxf(p0.w + q[c][0].w, 0.f);
      f[4] = fmaxf(p1.x + q[c][1].x, 0.f);
      f[5] = fmaxf(p1.y + q[c][1].y, 0.f);
      f[6] = fmaxf(p1.z + q[c][1].z, 0.f);
      f[7] = fmaxf(p1.w + q[c][1].w, 0.f);
      v8s bhi, blo;
      {
        unsigned* BH = (unsigned*)&bhi; unsigned* BL = (unsigned*)&blo;
#pragma unroll
        for (int jp = 0; jp < 4; ++jp)
          split2(f[2 * jp], f[2 * jp + 1], BH[jp], BL[jp]);
      }
      v4f a0 = bias0, a1 = bias1;
      a0 = __builtin_amdgcn_mfma_f32_16x16x32_bf16(whi0, bhi, a0, 0, 0, 0);
      a0 = __builtin_amdgcn_mfma_f32_16x16x32_bf16(whi0, blo, a0, 0, 0, 0);
      a0 = __builtin_amdgcn_mfma_f32_16x16x32_bf16(wlo0, bhi, a0, 0, 0, 0);
      a1 = __builtin_amdgcn_mfma_f32_16x16x32_bf16(whi1, bhi, a1, 0, 0, 0);
      a1 = __builtin_amdgcn_mfma_f32_16x16x32_bf16(whi1, blo, a1, 0, 0, 0);
      a1 = __builtin_amdgcn_mfma_f32_16x16x32_bf16(wlo1, bhi, a1, 0, 0, 0);

      float tacc = 0.f;
#pragma unroll
      for (int r = 0; r < 4; ++r) {
        tacc = fmaf(fmaxf(a0[r], 0.f), w3a[r], tacc);
        tacc = fmaf(fmaxf(a1[r], 0.f), w3b[r], tacc);
      }
      tacc += __shfl_xor(tacc, 16);
      tacc += __shfl_xor(tacc, 32);
      if (l < 16)
        out[outbase + (size_t)g1 * G + (2 * w + c) * 16 + l] = tacc + b3;
    }
  }
}

extern "C" void kernel_launch(void* const* d_in, const int* in_sizes, int n_in,
                              void* d_out, int out_size, void* d_ws, size_t ws_size,
                              hipStream_t stream) {
  const float* h     = (const float*)d_in[0];
  const int*   pp    = (const int*)d_in[1];
  const int*   pd    = (const int*)d_in[2];
  const int*   rec   = (const int*)d_in[3];
  const float* Wq1   = (const float*)d_in[4];
  const float* Wk1   = (const float*)d_in[5];
  const float* Wq2   = (const float*)d_in[6];
  const float* Wk2   = (const float*)d_in[7];
  const float* fc1_w = (const float*)d_in[8];
  const float* fc1_b = (const float*)d_in[9];
  const float* fc2_w = (const float*)d_in[10];
  const float* fc2_b = (const float*)d_in[11];
  const float* fc3_w = (const float*)d_in[12];
  const float* fc3_b = (const float*)d_in[13];
  float* out = (float*)d_out;
  float* ws  = (float*)d_ws;

  precompute_A<<<dim3(B), dim3(128), 0, stream>>>(h, pp, pd, Wq1, Wk1, Wq2, Wk2, ws);
  compute_PQ<<<dim3(256), dim3(256), 0, stream>>>(h, rec, fc1_w, fc1_b, ws);
  mlp_pairs<<<dim3(4, 32, 32), dim3(256), 0, stream>>>(
      ws, fc2_w, fc2_b, fc3_w, fc3_b, out);
}

// Round 5
// 156.896 us; speedup vs baseline: 2.5132x; 1.1474x over previous
//
#include <hip/hip_runtime.h>

// Reinsertion: B=32, G=512, D=128, H=4, KD=32. Output (B,G,G) fp32.
//
// R5 (= R3 + grid fix): stage-2 pair-MLP on v_mfma_f32_32x32x16_f16,
// single-term fp16 quantization of a=relu(P+Q) and W2 (v_cvt_pkrtz).
// Block covers 16 g1 x 256 g2 (4 waves x 2 chunks of 32) -> grid.x = G/256.

#define B 32
#define G 512
#define D 128
#define NH 4
#define KD 32
#define NORMF 0.17677669529663687f  // 1/sqrt(32)

#define WS_APQ 0
#define WS_APO 16384
#define WS_ADP 32768
#define WS_ADO 49152
#define WS_P   65536
#define WS_Q   589824

typedef float v16f __attribute__((ext_vector_type(16)));
typedef _Float16 v8h __attribute__((ext_vector_type(8)));
typedef __fp16 v2fp __attribute__((ext_vector_type(2)));  // cvt_pkrtz return type

union H8 { v8h v; v2fp h2[4]; };

// ---------------- Stage 0: per-batch A matrices (tiny) ----------------
__global__ __launch_bounds__(128) void precompute_A(
    const float* __restrict__ h, const int* __restrict__ pp, const int* __restrict__ pd,
    const float* __restrict__ Wq1, const float* __restrict__ Wk1,
    const float* __restrict__ Wq2, const float* __restrict__ Wk2,
    float* __restrict__ ws) {
  const int b = blockIdx.x;
  const int t = threadIdx.x;  // 0..127
  __shared__ float hp[D], hd[D];
  __shared__ float q1p[NH * KD], q2p[NH * KD], q1d[NH * KD], q2d[NH * KD];

  hp[t] = h[(b * G + pp[b]) * D + t];
  hd[t] = h[(b * G + pd[b]) * D + t];
  __syncthreads();

  {  // t -> (head hh, key k); dot over d
    const int hh = t >> 5, k = t & 31;
    const float* wq1 = Wq1 + hh * D * KD + k;
    const float* wq2 = Wq2 + hh * D * KD + k;
    float s1p = 0.f, s2p = 0.f, s1d = 0.f, s2d = 0.f;
    for (int d = 0; d < D; ++d) {
      const float w1 = wq1[d * KD], w2 = wq2[d * KD];
      const float xp = hp[d], xd = hd[d];
      s1p = fmaf(xp, w1, s1p);
      s2p = fmaf(xp, w2, s2p);
      s1d = fmaf(xd, w1, s1d);
      s2d = fmaf(xd, w2, s2d);
    }
    q1p[t] = s1p; q2p[t] = s2p; q1d[t] = s1d; q2d[t] = s2d;
  }
  __syncthreads();

  const int d = t;
  for (int hh = 0; hh < NH; ++hh) {
    const float* wk1 = Wk1 + hh * D * KD + d * KD;
    const float* wk2 = Wk2 + hh * D * KD + d * KD;
    float apq = 0.f, apo = 0.f, adp = 0.f, ado = 0.f;
#pragma unroll
    for (int k = 0; k < KD; ++k) {
      const float w1 = wk1[k], w2 = wk2[k];
      apq = fmaf(q1p[hh * 32 + k], w1, apq);
      adp = fmaf(q1d[hh * 32 + k], w1, adp);
      apo = fmaf(q2p[hh * 32 + k], w2, apo);
      ado = fmaf(q2d[hh * 32 + k], w2, ado);
    }
    const int o = b * (NH * D) + hh * D + d;
    ws[WS_APQ + o] = NORMF * apq;
    ws[WS_APO + o] = NORMF * apo;
    ws[WS_ADP + o] = NORMF * adp;
    ws[WS_ADO + o] = NORMF * ado;
  }
}

// ---------------- Stage 1: P and Q vectors ----------------
__global__ __launch_bounds__(256) void compute_PQ(
    const float* __restrict__ h, const int* __restrict__ rec,
    const float* __restrict__ fc1_w, const float* __restrict__ fc1_b,
    float* __restrict__ ws) {
  const int bx = blockIdx.x;
  const int b = bx >> 3, g0 = (bx & 7) * 64;
  const int t = threadIdx.x;
  const int gl = t & 63;
  const int hh = __builtin_amdgcn_readfirstlane(t >> 6);  // wave id == head
  const int g = g0 + gl;

  __shared__ float sc[64][17];
  __shared__ float sout[64][33];

  const float* Apq = ws + WS_APQ + (b * NH + hh) * D;
  const float* Apo = ws + WS_APO + (b * NH + hh) * D;
  const float* Adp = ws + WS_ADP + (b * NH + hh) * D;
  const float* Ado = ws + WS_ADO + (b * NH + hh) * D;
  const float4* hg4 = (const float4*)(h + ((size_t)b * G + g) * D);
  const float4* hn4 = (const float4*)(h + ((size_t)b * G + rec[b * G + g]) * D);

  float cpp = 0.f, cpo = 0.f, cdp = 0.f, cdo = 0.f;
#pragma unroll 4
  for (int d4 = 0; d4 < 32; ++d4) {
    const float4 x = hg4[d4], y = hn4[d4];
    const float4 a1 = *(const float4*)(Apq + d4 * 4);
    const float4 a2 = *(const float4*)(Apo + d4 * 4);
    const float4 a3 = *(const float4*)(Adp + d4 * 4);
    const float4 a4 = *(const float4*)(Ado + d4 * 4);
    cpp = fmaf(x.x, a1.x, fmaf(x.y, a1.y, fmaf(x.z, a1.z, fmaf(x.w, a1.w, cpp))));
    cpo = fmaf(y.x, a2.x, fmaf(y.y, a2.y, fmaf(y.z, a2.z, fmaf(y.w, a2.w, cpo))));
    cdp = fmaf(x.x, a3.x, fmaf(x.y, a3.y, fmaf(x.z, a3.z, fmaf(x.w, a3.w, cdp))));
    cdo = fmaf(y.x, a4.x, fmaf(y.y, a4.y, fmaf(y.z, a4.z, fmaf(y.w, a4.w, cdo))));
  }
  sc[gl][hh] = cpp; sc[gl][4 + hh] = cpo; sc[gl][8 + hh] = cdp; sc[gl][12 + hh] = cdo;
  __syncthreads();

  float u[16];
#pragma unroll
  for (int i = 0; i < 16; ++i) u[i] = sc[gl][i];

  float pv[8], qv[8];
#pragma unroll
  for (int jj = 0; jj < 8; ++jj) {
    const int j = hh * 8 + jj;  // wave-uniform -> s_load weights
    float p = 0.f, q = fc1_b[j];
#pragma unroll
    for (int i = 0; i < 8; ++i) {
      p = fmaf(u[i], fc1_w[i * 32 + j], p);
      q = fmaf(u[8 + i], fc1_w[(8 + i) * 32 + j], q);
    }
    pv[jj] = p; qv[jj] = q;
  }

#pragma unroll
  for (int jj = 0; jj < 8; ++jj) sout[gl][hh * 8 + jj] = pv[jj];
  __syncthreads();
  {
    float* dst = ws + WS_P + ((size_t)b * G + g0) * 32;
#pragma unroll
    for (int i = t; i < 2048; i += 256) dst[i] = sout[i >> 5][i & 31];
  }
  __syncthreads();
#pragma unroll
  for (int jj = 0; jj < 8; ++jj) sout[gl][hh * 8 + jj] = qv[jj];
  __syncthreads();
  {
    float* dst = ws + WS_Q + ((size_t)b * G + g0) * 32;
#pragma unroll
    for (int i = t; i < 2048; i += 256) dst[i] = sout[i >> 5][i & 31];
  }
}

// ---------------- Stage 2: per-pair MLP via 32x32x16 f16 MFMA ----------------
// Block: 256 thr = 4 waves; tile 16 g1 x 256 g2; wave w: g2 in
// [g2_0+64w, +64) as 2 chunks of 32. Per (g1, chunk): D[n][pair] =
// W2t(f16) x relu(P+Q)(f16), K=16 x2 MFMAs, acc seeded with fc2 bias.
// n-map per C/D layout: n = (r&3)+8*(r>>2)+4*(lane>>5), pair col = lane&31.
__global__ __launch_bounds__(256) void mlp_pairs(
    const float* __restrict__ ws,
    const float* __restrict__ fc2_w, const float* __restrict__ fc2_b,
    const float* __restrict__ fc3_w, const float* __restrict__ fc3_b,
    float* __restrict__ out) {
  const int b = blockIdx.z;
  const int g1_0 = blockIdx.y * 16;
  const int g2_0 = blockIdx.x * 256;
  const int t = threadIdx.x;
  const int w = t >> 6, l = t & 63;
  const int col = l & 31;          // pair (g2 offset within chunk)
  const int half = l >> 5;         // k-subrange selector
  const int kb = half * 8;

  __shared__ float sP[16 * 32];
  {
    const float* Pg = ws + WS_P + ((size_t)b * G + g1_0) * 32;
    sP[t] = Pg[t];
    sP[t + 256] = Pg[t + 256];
  }

  // Weight A-frags (f16, RTN): A[m=n=col][k = kb+j] ; k-halves 0..15 / 16..31
  v8h A0, A1;
#pragma unroll
  for (int j = 0; j < 8; ++j) {
    A0[j] = (_Float16)fc2_w[(kb + j) * 32 + col];
    A1[j] = (_Float16)fc2_w[(16 + kb + j) * 32 + col];
  }
  // Per-lane n-mapped bias / fc3 weights
  float biasv[16], w3v[16];
#pragma unroll
  for (int r = 0; r < 16; ++r) {
    const int n = (r & 3) + 8 * (r >> 2) + 4 * half;
    biasv[r] = fc2_b[n];
    w3v[r]   = fc3_w[n];
  }
  const float b3 = fc3_b[0];

  // Q fragments (g1-invariant): lane needs Q[g2][kb..kb+8) and [16+kb..+8)
  float4 q[2][4];
#pragma unroll
  for (int c = 0; c < 2; ++c) {
    const float* qp = ws + WS_Q +
        ((size_t)b * G + g2_0 + w * 64 + c * 32 + col) * 32;
    q[c][0] = *(const float4*)(qp + kb);
    q[c][1] = *(const float4*)(qp + kb + 4);
    q[c][2] = *(const float4*)(qp + 16 + kb);
    q[c][3] = *(const float4*)(qp + 16 + kb + 4);
  }
  __syncthreads();

  const size_t outbase = ((size_t)b * G + g1_0) * G + g2_0 + w * 64;
  for (int g1 = 0; g1 < 16; ++g1) {
    const float* pr = &sP[g1 * 32];
    const float4 p0 = *(const float4*)(pr + kb);
    const float4 p1 = *(const float4*)(pr + kb + 4);
    const float4 p2 = *(const float4*)(pr + 16 + kb);
    const float4 p3 = *(const float4*)(pr + 16 + kb + 4);

    float s[2];
#pragma unroll
    for (int c = 0; c < 2; ++c) {
      H8 B0, B1;
      B0.h2[0] = __builtin_amdgcn_cvt_pkrtz(fmaxf(p0.x + q[c][0].x, 0.f),
                                            fmaxf(p0.y + q[c][0].y, 0.f));
      B0.h2[1] = __builtin_amdgcn_cvt_pkrtz(fmaxf(p0.z + q[c][0].z, 0.f),
                                            fmaxf(p0.w + q[c][0].w, 0.f));
      B0.h2[2] = __builtin_amdgcn_cvt_pkrtz(fmaxf(p1.x + q[c][1].x, 0.f),
                                            fmaxf(p1.y + q[c][1].y, 0.f));
      B0.h2[3] = __builtin_amdgcn_cvt_pkrtz(fmaxf(p1.z + q[c][1].z, 0.f),
                                            fmaxf(p1.w + q[c][1].w, 0.f));
      B1.h2[0] = __builtin_amdgcn_cvt_pkrtz(fmaxf(p2.x + q[c][2].x, 0.f),
                                            fmaxf(p2.y + q[c][2].y, 0.f));
      B1.h2[1] = __builtin_amdgcn_cvt_pkrtz(fmaxf(p2.z + q[c][2].z, 0.f),
                                            fmaxf(p2.w + q[c][2].w, 0.f));
      B1.h2[2] = __builtin_amdgcn_cvt_pkrtz(fmaxf(p3.x + q[c][3].x, 0.f),
                                            fmaxf(p3.y + q[c][3].y, 0.f));
      B1.h2[3] = __builtin_amdgcn_cvt_pkrtz(fmaxf(p3.z + q[c][3].z, 0.f),
                                            fmaxf(p3.w + q[c][3].w, 0.f));

      v16f acc;
#pragma unroll
      for (int r = 0; r < 16; ++r) acc[r] = biasv[r];
      acc = __builtin_amdgcn_mfma_f32_32x32x16_f16(A0, B0.v, acc, 0, 0, 0);
      acc = __builtin_amdgcn_mfma_f32_32x32x16_f16(A1, B1.v, acc, 0, 0, 0);

      float sc = 0.f;
#pragma unroll
      for (int r = 0; r < 16; ++r)
        sc = fmaf(fmaxf(acc[r], 0.f), w3v[r], sc);
      s[c] = sc;
    }
    const float t0 = s[0] + __shfl_xor(s[0], 32);
    const float t1 = s[1] + __shfl_xor(s[1], 32);
    out[outbase + (size_t)g1 * G + l] = (l < 32 ? t0 : t1) + b3;
  }
}

extern "C" void kernel_launch(void* const* d_in, const int* in_sizes, int n_in,
                              void* d_out, int out_size, void* d_ws, size_t ws_size,
                              hipStream_t stream) {
  const float* h     = (const float*)d_in[0];
  const int*   pp    = (const int*)d_in[1];
  const int*   pd    = (const int*)d_in[2];
  const int*   rec   = (const int*)d_in[3];
  const float* Wq1   = (const float*)d_in[4];
  const float* Wk1   = (const float*)d_in[5];
  const float* Wq2   = (const float*)d_in[6];
  const float* Wk2   = (const float*)d_in[7];
  const float* fc1_w = (const float*)d_in[8];
  const float* fc1_b = (const float*)d_in[9];
  const float* fc2_w = (const float*)d_in[10];
  const float* fc2_b = (const float*)d_in[11];
  const float* fc3_w = (const float*)d_in[12];
  const float* fc3_b = (const float*)d_in[13];
  float* out = (float*)d_out;
  float* ws  = (float*)d_ws;

  precompute_A<<<dim3(B), dim3(128), 0, stream>>>(h, pp, pd, Wq1, Wk1, Wq2, Wk2, ws);
  compute_PQ<<<dim3(256), dim3(256), 0, stream>>>(h, rec, fc1_w, fc1_b, ws);
  mlp_pairs<<<dim3(2, 32, 32), dim3(256), 0, stream>>>(
      ws, fc2_w, fc2_b, fc3_w, fc3_b, out);
}

// Round 6
// 152.181 us; speedup vs baseline: 2.5911x; 1.0310x over previous
//
#include <hip/hip_runtime.h>

// Reinsertion: B=32, G=512, D=128, H=4, KD=32. Output (B,G,G) fp32.
//
// R6: stage-2 on v_mfma_f32_32x32x16_f16 with fp16 P/Q storage:
//  - B-form: v_pk_add_f16 + v_pk_max_f16 (relu) straight into MFMA B-frag.
//  - acc seeded by passing bias fragment as MFMA C operand (no init movs).
//  - fp16 A-frags/q halve register pressure (R5 showed spill symptoms:
//    215 dyn VALU/iter vs 93 static at VGPR_Count=68).

#define B 32
#define G 512
#define D 128
#define NH 4
#define KD 32
#define NORMF 0.17677669529663687f  // 1/sqrt(32)

// ws layout: floats [0,65536) = A tables; then fp16 P/Q.
#define WS_APQ 0
#define WS_APO 16384
#define WS_ADP 32768
#define WS_ADO 49152
#define WS_P16H 131072   // half-index of P (bytes 262144)
#define WS_Q16H 655360   // half-index of Q

typedef float v16f __attribute__((ext_vector_type(16)));
typedef _Float16 v8h __attribute__((ext_vector_type(8)));
typedef _Float16 h2 __attribute__((ext_vector_type(2)));

union Q8 {  // 16 bytes = 8 halves; uint4 member forces 16B alignment
  uint4 u;
  h2 h[4];
  v8h v;
};

// ---------------- Stage 0: per-batch A matrices (tiny) ----------------
__global__ __launch_bounds__(128) void precompute_A(
    const float* __restrict__ h, const int* __restrict__ pp, const int* __restrict__ pd,
    const float* __restrict__ Wq1, const float* __restrict__ Wk1,
    const float* __restrict__ Wq2, const float* __restrict__ Wk2,
    float* __restrict__ ws) {
  const int b = blockIdx.x;
  const int t = threadIdx.x;  // 0..127
  __shared__ float hp[D], hd[D];
  __shared__ float q1p[NH * KD], q2p[NH * KD], q1d[NH * KD], q2d[NH * KD];

  hp[t] = h[(b * G + pp[b]) * D + t];
  hd[t] = h[(b * G + pd[b]) * D + t];
  __syncthreads();

  {  // t -> (head hh, key k); dot over d
    const int hh = t >> 5, k = t & 31;
    const float* wq1 = Wq1 + hh * D * KD + k;
    const float* wq2 = Wq2 + hh * D * KD + k;
    float s1p = 0.f, s2p = 0.f, s1d = 0.f, s2d = 0.f;
    for (int d = 0; d < D; ++d) {
      const float w1 = wq1[d * KD], w2 = wq2[d * KD];
      const float xp = hp[d], xd = hd[d];
      s1p = fmaf(xp, w1, s1p);
      s2p = fmaf(xp, w2, s2p);
      s1d = fmaf(xd, w1, s1d);
      s2d = fmaf(xd, w2, s2d);
    }
    q1p[t] = s1p; q2p[t] = s2p; q1d[t] = s1d; q2d[t] = s2d;
  }
  __syncthreads();

  const int d = t;
  for (int hh = 0; hh < NH; ++hh) {
    const float* wk1 = Wk1 + hh * D * KD + d * KD;
    const float* wk2 = Wk2 + hh * D * KD + d * KD;
    float apq = 0.f, apo = 0.f, adp = 0.f, ado = 0.f;
#pragma unroll
    for (int k = 0; k < KD; ++k) {
      const float w1 = wk1[k], w2 = wk2[k];
      apq = fmaf(q1p[hh * 32 + k], w1, apq);
      adp = fmaf(q1d[hh * 32 + k], w1, adp);
      apo = fmaf(q2p[hh * 32 + k], w2, apo);
      ado = fmaf(q2d[hh * 32 + k], w2, ado);
    }
    const int o = b * (NH * D) + hh * D + d;
    ws[WS_APQ + o] = NORMF * apq;
    ws[WS_APO + o] = NORMF * apo;
    ws[WS_ADP + o] = NORMF * adp;
    ws[WS_ADO + o] = NORMF * ado;
  }
}

// ---------------- Stage 1: P and Q vectors (fp16 packed output) ----------------
__global__ __launch_bounds__(256) void compute_PQ(
    const float* __restrict__ h, const int* __restrict__ rec,
    const float* __restrict__ fc1_w, const float* __restrict__ fc1_b,
    float* __restrict__ ws) {
  const int bx = blockIdx.x;
  const int b = bx >> 3, g0 = (bx & 7) * 64;
  const int t = threadIdx.x;
  const int gl = t & 63;
  const int hh = __builtin_amdgcn_readfirstlane(t >> 6);  // wave id == head
  const int g = g0 + gl;

  __shared__ float sc[64][17];
  __shared__ float sout[64][33];

  const float* Apq = ws + WS_APQ + (b * NH + hh) * D;
  const float* Apo = ws + WS_APO + (b * NH + hh) * D;
  const float* Adp = ws + WS_ADP + (b * NH + hh) * D;
  const float* Ado = ws + WS_ADO + (b * NH + hh) * D;
  const float4* hg4 = (const float4*)(h + ((size_t)b * G + g) * D);
  const float4* hn4 = (const float4*)(h + ((size_t)b * G + rec[b * G + g]) * D);

  float cpp = 0.f, cpo = 0.f, cdp = 0.f, cdo = 0.f;
#pragma unroll 4
  for (int d4 = 0; d4 < 32; ++d4) {
    const float4 x = hg4[d4], y = hn4[d4];
    const float4 a1 = *(const float4*)(Apq + d4 * 4);
    const float4 a2 = *(const float4*)(Apo + d4 * 4);
    const float4 a3 = *(const float4*)(Adp + d4 * 4);
    const float4 a4 = *(const float4*)(Ado + d4 * 4);
    cpp = fmaf(x.x, a1.x, fmaf(x.y, a1.y, fmaf(x.z, a1.z, fmaf(x.w, a1.w, cpp))));
    cpo = fmaf(y.x, a2.x, fmaf(y.y, a2.y, fmaf(y.z, a2.z, fmaf(y.w, a2.w, cpo))));
    cdp = fmaf(x.x, a3.x, fmaf(x.y, a3.y, fmaf(x.z, a3.z, fmaf(x.w, a3.w, cdp))));
    cdo = fmaf(y.x, a4.x, fmaf(y.y, a4.y, fmaf(y.z, a4.z, fmaf(y.w, a4.w, cdo))));
  }
  sc[gl][hh] = cpp; sc[gl][4 + hh] = cpo; sc[gl][8 + hh] = cdp; sc[gl][12 + hh] = cdo;
  __syncthreads();

  float u[16];
#pragma unroll
  for (int i = 0; i < 16; ++i) u[i] = sc[gl][i];

  float pv[8], qv[8];
#pragma unroll
  for (int jj = 0; jj < 8; ++jj) {
    const int j = hh * 8 + jj;  // wave-uniform -> s_load weights
    float p = 0.f, q = fc1_b[j];
#pragma unroll
    for (int i = 0; i < 8; ++i) {
      p = fmaf(u[i], fc1_w[i * 32 + j], p);
      q = fmaf(u[8 + i], fc1_w[(8 + i) * 32 + j], q);
    }
    pv[jj] = p; qv[jj] = q;
  }

  // P: transpose through LDS, pack to fp16 on the way out (coalesced uints)
#pragma unroll
  for (int jj = 0; jj < 8; ++jj) sout[gl][hh * 8 + jj] = pv[jj];
  __syncthreads();
  {
    unsigned* dst = (unsigned*)((unsigned short*)ws + WS_P16H) +
                    ((size_t)b * G + g0) * 16;
#pragma unroll
    for (int i = t; i < 1024; i += 256) {
      const int row = i >> 4, c0 = (2 * i) & 31;
      __fp16 __attribute__((ext_vector_type(2))) pk =
          __builtin_amdgcn_cvt_pkrtz(sout[row][c0], sout[row][c0 + 1]);
      dst[i] = *(const unsigned*)&pk;
    }
  }
  __syncthreads();
#pragma unroll
  for (int jj = 0; jj < 8; ++jj) sout[gl][hh * 8 + jj] = qv[jj];
  __syncthreads();
  {
    unsigned* dst = (unsigned*)((unsigned short*)ws + WS_Q16H) +
                    ((size_t)b * G + g0) * 16;
#pragma unroll
    for (int i = t; i < 1024; i += 256) {
      const int row = i >> 4, c0 = (2 * i) & 31;
      __fp16 __attribute__((ext_vector_type(2))) pk =
          __builtin_amdgcn_cvt_pkrtz(sout[row][c0], sout[row][c0 + 1]);
      dst[i] = *(const unsigned*)&pk;
    }
  }
}

// ---------------- Stage 2: per-pair MLP via 32x32x16 f16 MFMA ----------------
// Block: 256 thr = 4 waves; tile 16 g1 x 256 g2; wave w: chunks {2w,2w+1} of
// 32 g2. Per (g1, chunk): B = relu(P+Q) formed with pk f16 ops; acc =
// mfma(A0,B0,biasC); acc = mfma(A1,B1,acc); epilogue relu-dot fc3.
__global__ __launch_bounds__(256) void mlp_pairs(
    const float* __restrict__ ws,
    const float* __restrict__ fc2_w, const float* __restrict__ fc2_b,
    const float* __restrict__ fc3_w, const float* __restrict__ fc3_b,
    float* __restrict__ out) {
  const int b = blockIdx.z;
  const int g1_0 = blockIdx.y * 16;
  const int g2_0 = blockIdx.x * 256;
  const int t = threadIdx.x;
  const int w = t >> 6, l = t & 63;
  const int col = l & 31;          // pair (g2 offset within chunk)
  const int half = l >> 5;         // k-subrange selector
  const int kb = half * 8;

  __shared__ __align__(16) unsigned short sPh[16 * 32];  // 1 KB fp16 P tile
  {
    const unsigned* Psrc = (const unsigned*)((const unsigned short*)ws + WS_P16H) +
                           ((size_t)b * G + g1_0) * 16;
    ((unsigned*)sPh)[t] = Psrc[t];
  }

  // Weight A-frags (f16): A[m=n-col][k=kb+j] = fc2_w[(k)*32+col]
  v8h A0, A1;
#pragma unroll
  for (int j = 0; j < 8; ++j) {
    A0[j] = (_Float16)fc2_w[(kb + j) * 32 + col];
    A1[j] = (_Float16)fc2_w[(16 + kb + j) * 32 + col];
  }
  // Bias as MFMA C-seed fragment; fc3 weights per-lane (n-mapped)
  v16f biasC;
  float w3v[16];
#pragma unroll
  for (int r = 0; r < 16; ++r) {
    const int n = (r & 3) + 8 * (r >> 2) + 4 * half;
    biasC[r] = fc2_b[n];
    w3v[r]   = fc3_w[n];
  }
  const float b3 = fc3_b[0];

  // Q fragments fp16 (g1-invariant): per chunk, k ranges [kb,kb+8) & [16+kb,+8)
  Q8 q0[2], q1[2];
#pragma unroll
  for (int c = 0; c < 2; ++c) {
    const unsigned short* qp = (const unsigned short*)ws + WS_Q16H +
        ((size_t)b * G + g2_0 + (2 * w + c) * 32 + col) * 32;
    q0[c].u = *(const uint4*)(qp + kb);
    q1[c].u = *(const uint4*)(qp + 16 + kb);
  }
  __syncthreads();

  const h2 zero = {(_Float16)0.0f, (_Float16)0.0f};
  const size_t outbase = ((size_t)b * G + g1_0) * G + g2_0 + w * 64;
  for (int g1 = 0; g1 < 16; ++g1) {
    const Q8 p0 = *(const Q8*)(sPh + g1 * 32 + kb);
    const Q8 p1 = *(const Q8*)(sPh + g1 * 32 + 16 + kb);

    float s[2];
#pragma unroll
    for (int c = 0; c < 2; ++c) {
      Q8 B0, B1;
#pragma unroll
      for (int i = 0; i < 4; ++i) {
        B0.h[i] = __builtin_elementwise_max(p0.h[i] + q0[c].h[i], zero);
        B1.h[i] = __builtin_elementwise_max(p1.h[i] + q1[c].h[i], zero);
      }
      v16f acc = __builtin_amdgcn_mfma_f32_32x32x16_f16(A0, B0.v, biasC, 0, 0, 0);
      acc = __builtin_amdgcn_mfma_f32_32x32x16_f16(A1, B1.v, acc, 0, 0, 0);

      float e0 = 0.f, e1 = 0.f;
#pragma unroll
      for (int r = 0; r < 16; r += 2) {
        e0 = fmaf(fmaxf(acc[r], 0.f), w3v[r], e0);
        e1 = fmaf(fmaxf(acc[r + 1], 0.f), w3v[r + 1], e1);
      }
      s[c] = e0 + e1;
    }
    const float t0 = s[0] + __shfl_xor(s[0], 32);
    const float t1 = s[1] + __shfl_xor(s[1], 32);
    out[outbase + (size_t)g1 * G + l] = (l < 32 ? t0 : t1) + b3;
  }
}

extern "C" void kernel_launch(void* const* d_in, const int* in_sizes, int n_in,
                              void* d_out, int out_size, void* d_ws, size_t ws_size,
                              hipStream_t stream) {
  const float* h     = (const float*)d_in[0];
  const int*   pp    = (const int*)d_in[1];
  const int*   pd    = (const int*)d_in[2];
  const int*   rec   = (const int*)d_in[3];
  const float* Wq1   = (const float*)d_in[4];
  const float* Wk1   = (const float*)d_in[5];
  const float* Wq2   = (const float*)d_in[6];
  const float* Wk2   = (const float*)d_in[7];
  const float* fc1_w = (const float*)d_in[8];
  const float* fc1_b = (const float*)d_in[9];
  const float* fc2_w = (const float*)d_in[10];
  const float* fc2_b = (const float*)d_in[11];
  const float* fc3_w = (const float*)d_in[12];
  const float* fc3_b = (const float*)d_in[13];
  float* out = (float*)d_out;
  float* ws  = (float*)d_ws;

  precompute_A<<<dim3(B), dim3(128), 0, stream>>>(h, pp, pd, Wq1, Wk1, Wq2, Wk2, ws);
  compute_PQ<<<dim3(256), dim3(256), 0, stream>>>(h, rec, fc1_w, fc1_b, ws);
  mlp_pairs<<<dim3(2, 32, 32), dim3(256), 0, stream>>>(
      ws, fc2_w, fc2_b, fc3_w, fc3_b, out);
}

// Round 7
// 148.945 us; speedup vs baseline: 2.6473x; 1.0217x over previous
//
#include <hip/hip_runtime.h>

// Reinsertion: B=32, G=512, D=128, H=4, KD=32. Output (B,G,G) fp32.
//
// R7: (1) stage0 fused into stage1 (A-tables recomputed per block in LDS);
// (2) mlp_pairs: wave = one 32-g2 chunk, 2 g1 rows per iteration -> two
// independent MFMA chains, epilogue(a) overlaps MFMA(b), full-wave stores;
// (3) union-free bit_cast fragments.

#define B 32
#define G 512
#define D 128
#define NH 4
#define KD 32
#define NORMF 0.17677669529663687f  // 1/sqrt(32)

// ws: fp16 P/Q only (half-indices)
#define WS_P16H 131072
#define WS_Q16H 655360

typedef float v16f __attribute__((ext_vector_type(16)));
typedef _Float16 v8h __attribute__((ext_vector_type(8)));
typedef _Float16 h2v __attribute__((ext_vector_type(2)));

struct HQ { h2v h[4]; };  // 8 halves = 4 VGPRs

__device__ __forceinline__ v8h relu_add(const HQ& p, const HQ& q) {
  const h2v z = {(_Float16)0.0f, (_Float16)0.0f};
  HQ r;
#pragma unroll
  for (int i = 0; i < 4; ++i)
    r.h[i] = __builtin_elementwise_max(p.h[i] + q.h[i], z);
  return __builtin_bit_cast(v8h, r);
}

// ---------------- Stage 0+1 fused: A-tables (LDS) + P/Q vectors ----------------
__global__ __launch_bounds__(256) void stage01(
    const float* __restrict__ h, const int* __restrict__ pp,
    const int* __restrict__ pd, const int* __restrict__ rec,
    const float* __restrict__ Wq1, const float* __restrict__ Wk1,
    const float* __restrict__ Wq2, const float* __restrict__ Wk2,
    const float* __restrict__ fc1_w, const float* __restrict__ fc1_b,
    float* __restrict__ ws) {
  const int bx = blockIdx.x;
  const int b = bx >> 3, g0 = (bx & 7) * 64;
  const int t = threadIdx.x;

  __shared__ float hp[D], hd[D];
  __shared__ float qq[4][NH * KD];   // q1p,q2p,q1d,q2d
  __shared__ float sA[4][NH][D];     // Apq,Apo,Adp,Ado
  __shared__ float sc[64][17];
  __shared__ float sout[64][33];

  if (t < 128) {
    hp[t] = h[((size_t)b * G + pp[b]) * D + t];
  } else {
    const int u = t - 128;
    hd[u] = h[((size_t)b * G + pd[b]) * D + u];
  }
  __syncthreads();

  if (t < 128) {  // t -> (head hh, key k); dot over d
    const int hh = t >> 5, k = t & 31;
    const float* wq1 = Wq1 + hh * D * KD + k;
    const float* wq2 = Wq2 + hh * D * KD + k;
    float s1p = 0.f, s2p = 0.f, s1d = 0.f, s2d = 0.f;
    for (int d = 0; d < D; ++d) {
      const float w1 = wq1[d * KD], w2 = wq2[d * KD];
      const float xp = hp[d], xd = hd[d];
      s1p = fmaf(xp, w1, s1p);
      s2p = fmaf(xp, w2, s2p);
      s1d = fmaf(xd, w1, s1d);
      s2d = fmaf(xd, w2, s2d);
    }
    qq[0][t] = s1p; qq[1][t] = s2p; qq[2][t] = s1d; qq[3][t] = s2d;
  }
  __syncthreads();

  {  // A[table][hh][d]; thread t: d = t&127, two heads
    const int d = t & 127;
    const int h0 = (t >> 7) * 2;
#pragma unroll
    for (int hh = h0; hh < h0 + 2; ++hh) {
      const float* wk1 = Wk1 + hh * D * KD + d * KD;
      const float* wk2 = Wk2 + hh * D * KD + d * KD;
      float apq = 0.f, apo = 0.f, adp = 0.f, ado = 0.f;
#pragma unroll
      for (int k = 0; k < KD; ++k) {
        const float w1 = wk1[k], w2 = wk2[k];
        apq = fmaf(qq[0][hh * 32 + k], w1, apq);
        adp = fmaf(qq[2][hh * 32 + k], w1, adp);
        apo = fmaf(qq[1][hh * 32 + k], w2, apo);
        ado = fmaf(qq[3][hh * 32 + k], w2, ado);
      }
      sA[0][hh][d] = NORMF * apq;
      sA[1][hh][d] = NORMF * apo;
      sA[2][hh][d] = NORMF * adp;
      sA[3][hh][d] = NORMF * ado;
    }
  }
  __syncthreads();

  // Phase B: compat dots + fc1 decomposition
  const int gl = t & 63;
  const int hh = __builtin_amdgcn_readfirstlane(t >> 6);  // wave id == head
  const int g = g0 + gl;
  const float4* hg4 = (const float4*)(h + ((size_t)b * G + g) * D);
  const float4* hn4 = (const float4*)(h + ((size_t)b * G + rec[b * G + g]) * D);

  float cpp = 0.f, cpo = 0.f, cdp = 0.f, cdo = 0.f;
#pragma unroll 4
  for (int d4 = 0; d4 < 32; ++d4) {
    const float4 x = hg4[d4], y = hn4[d4];
    const float4 a1 = *(const float4*)&sA[0][hh][4 * d4];
    const float4 a2 = *(const float4*)&sA[1][hh][4 * d4];
    const float4 a3 = *(const float4*)&sA[2][hh][4 * d4];
    const float4 a4 = *(const float4*)&sA[3][hh][4 * d4];
    cpp = fmaf(x.x, a1.x, fmaf(x.y, a1.y, fmaf(x.z, a1.z, fmaf(x.w, a1.w, cpp))));
    cpo = fmaf(y.x, a2.x, fmaf(y.y, a2.y, fmaf(y.z, a2.z, fmaf(y.w, a2.w, cpo))));
    cdp = fmaf(x.x, a3.x, fmaf(x.y, a3.y, fmaf(x.z, a3.z, fmaf(x.w, a3.w, cdp))));
    cdo = fmaf(y.x, a4.x, fmaf(y.y, a4.y, fmaf(y.z, a4.z, fmaf(y.w, a4.w, cdo))));
  }
  sc[gl][hh] = cpp; sc[gl][4 + hh] = cpo; sc[gl][8 + hh] = cdp; sc[gl][12 + hh] = cdo;
  __syncthreads();

  float u[16];
#pragma unroll
  for (int i = 0; i < 16; ++i) u[i] = sc[gl][i];

  float pv[8], qv[8];
#pragma unroll
  for (int jj = 0; jj < 8; ++jj) {
    const int j = hh * 8 + jj;  // wave-uniform -> s_load weights
    float p = 0.f, q = fc1_b[j];
#pragma unroll
    for (int i = 0; i < 8; ++i) {
      p = fmaf(u[i], fc1_w[i * 32 + j], p);
      q = fmaf(u[8 + i], fc1_w[(8 + i) * 32 + j], q);
    }
    pv[jj] = p; qv[jj] = q;
  }

  // pack to fp16, transpose via LDS, coalesced uint stores
#pragma unroll
  for (int jj = 0; jj < 8; ++jj) sout[gl][hh * 8 + jj] = pv[jj];
  __syncthreads();
  {
    unsigned* dst = (unsigned*)((unsigned short*)ws + WS_P16H) +
                    ((size_t)b * G + g0) * 16;
#pragma unroll
    for (int i = t; i < 1024; i += 256) {
      const int row = i >> 4, c0 = (2 * i) & 31;
      __fp16 __attribute__((ext_vector_type(2))) pk =
          __builtin_amdgcn_cvt_pkrtz(sout[row][c0], sout[row][c0 + 1]);
      dst[i] = *(const unsigned*)&pk;
    }
  }
  __syncthreads();
#pragma unroll
  for (int jj = 0; jj < 8; ++jj) sout[gl][hh * 8 + jj] = qv[jj];
  __syncthreads();
  {
    unsigned* dst = (unsigned*)((unsigned short*)ws + WS_Q16H) +
                    ((size_t)b * G + g0) * 16;
#pragma unroll
    for (int i = t; i < 1024; i += 256) {
      const int row = i >> 4, c0 = (2 * i) & 31;
      __fp16 __attribute__((ext_vector_type(2))) pk =
          __builtin_amdgcn_cvt_pkrtz(sout[row][c0], sout[row][c0 + 1]);
      dst[i] = *(const unsigned*)&pk;
    }
  }
}

// ---------------- Stage 2: per-pair MLP via 32x32x16 f16 MFMA ----------------
// Grid (4,32,32); block 256 = 4 waves; wave w owns g2 chunk
// [bx*128 + 32w, +32). Iteration i handles g1 rows {2i, 2i+1}: two
// independent 2-MFMA chains; epilogue(a) overlaps mfma(b) latency.
// Store: half 0 lanes -> row 2i, half 1 -> row 2i+1 (full-wave store).
__global__ __launch_bounds__(256) void mlp_pairs(
    const float* __restrict__ ws,
    const float* __restrict__ fc2_w, const float* __restrict__ fc2_b,
    const float* __restrict__ fc3_w, const float* __restrict__ fc3_b,
    float* __restrict__ out) {
  const int b = blockIdx.z;
  const int g1_0 = blockIdx.y * 16;
  const int g2_0 = blockIdx.x * 128;
  const int t = threadIdx.x;
  const int w = t >> 6, l = t & 63;
  const int col = l & 31;   // pair within chunk
  const int half = l >> 5;  // k-subrange selector (B-layout lane half)
  const int kb = half * 8;

  __shared__ __align__(16) unsigned short sPh[16 * 32];  // 1 KB P tile
  {
    const unsigned* Psrc = (const unsigned*)((const unsigned short*)ws + WS_P16H) +
                           ((size_t)b * G + g1_0) * 16;
    ((unsigned*)sPh)[t] = Psrc[t];
  }

  // A-frags: W2t[n=col][k = kb+j] (f16 RTN); k-halves [0,16) / [16,32)
  v8h A0, A1;
#pragma unroll
  for (int j = 0; j < 8; ++j) {
    A0[j] = (_Float16)fc2_w[(kb + j) * 32 + col];
    A1[j] = (_Float16)fc2_w[(16 + kb + j) * 32 + col];
  }
  // Bias as C-seed; fc3 weights per-lane (n-mapped)
  v16f biasC;
  float w3v[16];
#pragma unroll
  for (int r = 0; r < 16; ++r) {
    const int n = (r & 3) + 8 * (r >> 2) + 4 * half;
    biasC[r] = fc2_b[n];
    w3v[r]   = fc3_w[n];
  }
  const float b3 = fc3_b[0];

  // Q fragments (g1-invariant, fp16): k ranges [kb,kb+8) and [16+kb,+8)
  HQ qlo, qhi;
  {
    const unsigned short* qp = (const unsigned short*)ws + WS_Q16H +
        ((size_t)b * G + g2_0 + w * 32 + col) * 32;
    qlo = __builtin_bit_cast(HQ, *(const uint4*)(qp + kb));
    qhi = __builtin_bit_cast(HQ, *(const uint4*)(qp + 16 + kb));
  }
  __syncthreads();

  float* op = out + (((size_t)b * G + g1_0 + half) * G) + g2_0 + w * 32 + col;
#pragma unroll
  for (int i = 0; i < 8; ++i) {
    const int ra = 2 * i, rb = 2 * i + 1;
    const HQ palo = __builtin_bit_cast(HQ, *(const uint4*)(sPh + ra * 32 + kb));
    const HQ pahi = __builtin_bit_cast(HQ, *(const uint4*)(sPh + ra * 32 + 16 + kb));
    const HQ pblo = __builtin_bit_cast(HQ, *(const uint4*)(sPh + rb * 32 + kb));
    const HQ pbhi = __builtin_bit_cast(HQ, *(const uint4*)(sPh + rb * 32 + 16 + kb));

    const v8h Balo = relu_add(palo, qlo);
    const v8h Bahi = relu_add(pahi, qhi);
    const v8h Bblo = relu_add(pblo, qlo);
    const v8h Bbhi = relu_add(pbhi, qhi);

    v16f acca = __builtin_amdgcn_mfma_f32_32x32x16_f16(A0, Balo, biasC, 0, 0, 0);
    v16f accb = __builtin_amdgcn_mfma_f32_32x32x16_f16(A0, Bblo, biasC, 0, 0, 0);
    acca = __builtin_amdgcn_mfma_f32_32x32x16_f16(A1, Bahi, acca, 0, 0, 0);
    accb = __builtin_amdgcn_mfma_f32_32x32x16_f16(A1, Bbhi, accb, 0, 0, 0);

    float a0 = 0.f, a1 = 0.f, b0 = 0.f, b1 = 0.f;
#pragma unroll
    for (int r = 0; r < 16; r += 2) {
      a0 = fmaf(fmaxf(acca[r], 0.f), w3v[r], a0);
      a1 = fmaf(fmaxf(acca[r + 1], 0.f), w3v[r + 1], a1);
      b0 = fmaf(fmaxf(accb[r], 0.f), w3v[r], b0);
      b1 = fmaf(fmaxf(accb[r + 1], 0.f), w3v[r + 1], b1);
    }
    float sa = a0 + a1, sb = b0 + b1;
    sa += __shfl_xor(sa, 32);
    sb += __shfl_xor(sb, 32);
    // half 0 lanes: row ra; half 1 lanes: row rb (op already offset by half*G)
    op[(size_t)ra * G] = (half ? sb : sa) + b3;
  }
}

extern "C" void kernel_launch(void* const* d_in, const int* in_sizes, int n_in,
                              void* d_out, int out_size, void* d_ws, size_t ws_size,
                              hipStream_t stream) {
  const float* h     = (const float*)d_in[0];
  const int*   pp    = (const int*)d_in[1];
  const int*   pd    = (const int*)d_in[2];
  const int*   rec   = (const int*)d_in[3];
  const float* Wq1   = (const float*)d_in[4];
  const float* Wk1   = (const float*)d_in[5];
  const float* Wq2   = (const float*)d_in[6];
  const float* Wk2   = (const float*)d_in[7];
  const float* fc1_w = (const float*)d_in[8];
  const float* fc1_b = (const float*)d_in[9];
  const float* fc2_w = (const float*)d_in[10];
  const float* fc2_b = (const float*)d_in[11];
  const float* fc3_w = (const float*)d_in[12];
  const float* fc3_b = (const float*)d_in[13];
  float* out = (float*)d_out;
  float* ws  = (float*)d_ws;

  stage01<<<dim3(256), dim3(256), 0, stream>>>(
      h, pp, pd, rec, Wq1, Wk1, Wq2, Wk2, fc1_w, fc1_b, ws);
  mlp_pairs<<<dim3(4, 32, 32), dim3(256), 0, stream>>>(
      ws, fc2_w, fc2_b, fc3_w, fc3_b, out);
}